// Round 4
// baseline (1363.759 us; speedup 1.0000x reference)
//
#include <hip/hip_runtime.h>
#include <hip/hip_bf16.h>

#define NH 80
#define NKV 8
#define HD 128
#define GROUPS 10
#define SEQ 1024
#define BATCH 2
#define DMODEL 5120
#define NQKV 12288   // 10240 q + 1024 k + 1024 v
#define MROWS 2048   // B*S
#define QCOLS 10240
#define KOFF 10240
#define VOFF 11264
#define ATTN_SCALE 0.08838834764831845f  // 128^-0.5

typedef __attribute__((ext_vector_type(8))) __bf16 bf16x8;
typedef __attribute__((ext_vector_type(4))) float f32x4;

__device__ inline unsigned short f2bf(float f) {
  unsigned u = __float_as_uint(f);
  u = (u + 0x7fffu + ((u >> 16) & 1u)) >> 16;
  return (unsigned short)u;
}
__device__ inline float bf2f(unsigned short h) {
  return __uint_as_float(((unsigned)h) << 16);
}

template <typename T>
__device__ inline T ld_vec(const void* p) {
  T v;
  __builtin_memcpy(&v, p, sizeof(T));
  return v;
}

__device__ inline void gload_lds16(const void* g, void* l) {
  __builtin_amdgcn_global_load_lds(
      (const __attribute__((address_space(1))) void*)g,
      (__attribute__((address_space(3))) void*)l, 16, 0, 0);
}

#define BAR() __builtin_amdgcn_s_barrier()
#define WAITLG0()                                     \
  do {                                                \
    asm volatile("s_waitcnt lgkmcnt(0)" ::: "memory");\
    __builtin_amdgcn_sched_barrier(0);                \
  } while (0)
#define WAITVM2() asm volatile("s_waitcnt vmcnt(2)" ::: "memory")

// ---------------- fp32 -> bf16 conversion (8 elems/thread) ----------------
__global__ __launch_bounds__(256) void cvt_f32_bf16(
    const float* __restrict__ src, unsigned short* __restrict__ dst, long n) {
  long i = ((long)blockIdx.x * 256 + threadIdx.x) * 8;
  if (i + 8 > n) return;
  float4 a = *reinterpret_cast<const float4*>(src + i);
  float4 b = *reinterpret_cast<const float4*>(src + i + 4);
  union { unsigned short u[8]; uint4 v; } r;
  r.u[0] = f2bf(a.x); r.u[1] = f2bf(a.y); r.u[2] = f2bf(a.z); r.u[3] = f2bf(a.w);
  r.u[4] = f2bf(b.x); r.u[5] = f2bf(b.y); r.u[6] = f2bf(b.z); r.u[7] = f2bf(b.w);
  *reinterpret_cast<uint4*>(dst + i) = r.v;
}

__global__ __launch_bounds__(256) void concat_bias(
    const float* __restrict__ qb, const float* __restrict__ kb,
    const float* __restrict__ vb, float* __restrict__ out) {
  int i = blockIdx.x * 256 + threadIdx.x;
  if (i >= NQKV) return;
  float v;
  if (i < KOFF) v = qb[i];
  else if (i < VOFF) v = kb[i - KOFF];
  else v = vb[i - VOFF];
  out[i] = v;
}

// ---------------- even-phase 256x256 GEMM: C = A[M,K] * W[N,K]^T -----------
// 512 thr = 8 waves (2M x 4N), per-wave C = 128x64, BK=64.
// 4 phases per K-tile, quadrants (rf-half x ks); each phase reads exactly what
// its 16 MFMAs consume (4-8 ds_read_b128) and issues one 8KB stage unit.
// Skewed A/B staging rings, one counted vmcnt(2) per tile (never 0).
// Bank swizzle: col_byte ^= ((row&7)<<4) on read and on global source.
template <int OUT_BF16, int HAS_BIAS>
__global__ __launch_bounds__(512, 2) void gemm8(
    const unsigned short* __restrict__ A, const unsigned short* __restrict__ W,
    const float* __restrict__ bias, void* __restrict__ Cout,
    int M, int N, int K, int NBN) {
  __shared__ unsigned short lds[2][2][16384];  // [buf][A/B][256 rows x 128B]
  const int t = threadIdx.x, lane = t & 63, w = t >> 6;
  const int wm = w >> 2, wn = w & 3;
  const int lr = lane & 15, lg = lane >> 4;
  // bijective XCD-aware tile swizzle (m204)
  const int nwg = gridDim.x, bid = blockIdx.x;
  const int q = nwg >> 3, r = nwg & 7;
  const int xcd = bid & 7, lx = bid >> 3;
  const int wg = (xcd < r ? xcd * (q + 1) : r * (q + 1) + (xcd - r) * q) + lx;
  const int tm = wg / NBN, tn = wg % NBN;
  // staging source pointers [mat][half][chunk]; source carries the involution.
  const char* sp[2][2][2];
  int so_row[2], so_col[2];
#pragma unroll
  for (int c = 0; c < 2; ++c) {
    int o = c * 8192 + w * 1024 + lane * 16;  // dest byte in 16KB half
    int rr = o >> 7, cp = o & 127;
    so_row[c] = rr;
    so_col[c] = cp ^ ((rr & 7) << 4);
  }
#pragma unroll
  for (int mat = 0; mat < 2; ++mat)
#pragma unroll
    for (int half = 0; half < 2; ++half)
#pragma unroll
      for (int c = 0; c < 2; ++c) {
        size_t row = (size_t)(mat ? tn : tm) * 256 + half * 128 + so_row[c];
        sp[mat][half][c] =
            (const char*)(mat ? W : A) + row * (size_t)K * 2 + so_col[c];
      }
  auto STG_A = [&](int buf, int half, int kt) {
    char* lb = (char*)&lds[buf][0][0] + half * 16384 + w * 1024;
    gload_lds16(sp[0][half][0] + (size_t)kt * 128, lb);
    gload_lds16(sp[0][half][1] + (size_t)kt * 128, lb + 8192);
  };
  auto STG_B = [&](int buf, int half, int kt) {
    char* lb = (char*)&lds[buf][1][0] + half * 16384 + w * 1024;
    gload_lds16(sp[1][half][0] + (size_t)kt * 128, lb);
    gload_lds16(sp[1][half][1] + (size_t)kt * 128, lb + 8192);
  };
  const int swz = (lane & 7) << 4;  // row&7 == lane&7 for all fragment rows
  bf16x8 aL[4], aH[4], b0[4], b1[4];
  auto LDA4 = [&](bf16x8* dst, int buf, int ks, int rfh) {
    const char* base = (const char*)&lds[buf][0][0];
    int colb = (ks * 64 + lg * 16) ^ swz;
#pragma unroll
    for (int f = 0; f < 4; ++f)
      dst[f] = ld_vec<bf16x8>(base + (wm * 128 + rfh * 64 + f * 16 + lr) * 128 + colb);
  };
  auto LDB4 = [&](bf16x8* dst, int buf, int ks) {
    const char* base = (const char*)&lds[buf][1][0];
    int colb = (ks * 64 + lg * 16) ^ swz;
#pragma unroll
    for (int f = 0; f < 4; ++f)
      dst[f] = ld_vec<bf16x8>(base + (wn * 64 + f * 16 + lr) * 128 + colb);
  };
  f32x4 acc[8][4] = {};
  auto MM_LO = [&](bf16x8* aF, bf16x8* bF) {
    __builtin_amdgcn_s_setprio(1);
#pragma unroll
    for (int rf = 0; rf < 4; ++rf)
#pragma unroll
      for (int cf = 0; cf < 4; ++cf)
        acc[rf][cf] = __builtin_amdgcn_mfma_f32_16x16x32_bf16(
            aF[rf], bF[cf], acc[rf][cf], 0, 0, 0);
    __builtin_amdgcn_s_setprio(0);
  };
  auto MM_HI = [&](bf16x8* aF, bf16x8* bF) {
    __builtin_amdgcn_s_setprio(1);
#pragma unroll
    for (int rf = 0; rf < 4; ++rf)
#pragma unroll
      for (int cf = 0; cf < 4; ++cf)
        acc[4 + rf][cf] = __builtin_amdgcn_mfma_f32_16x16x32_bf16(
            aF[rf], bF[cf], acc[4 + rf][cf], 0, 0, 0);
    __builtin_amdgcn_s_setprio(0);
  };
  // one K-tile: 4 even phases. BUF computed; OB=1-BUF staged.
  // stage table: ph1 A(next)h0->OB, ph2 A(next)h1->OB, ph3 B(next)h1->OB,
  //              ph4 B(next2)h0->BUF, then vmcnt(2).
  auto TILE = [&](int BUF, int OB, int ktA, int ktB2) {
    LDA4(aL, BUF, 0, 0); LDB4(b0, BUF, 0);
    STG_A(OB, 0, ktA);
    BAR(); WAITLG0(); MM_LO(aL, b0); BAR();
    LDA4(aH, BUF, 0, 1);
    STG_A(OB, 1, ktA);
    BAR(); WAITLG0(); MM_HI(aH, b0); BAR();
    LDA4(aL, BUF, 1, 0); LDB4(b1, BUF, 1);
    STG_B(OB, 1, ktA);
    BAR(); WAITLG0(); MM_LO(aL, b1); BAR();
    LDA4(aH, BUF, 1, 1);
    STG_B(BUF, 0, ktB2);
    BAR(); WAITLG0(); MM_HI(aH, b1); WAITVM2(); BAR();
  };

  const int NT = K >> 6, NIT = NT >> 1;
  // prologue: A(0),B(0) full + B(1)h0; leave B(1)h0 in flight (invariant).
  STG_A(0, 0, 0); STG_A(0, 1, 0);
  STG_B(0, 0, 0); STG_B(0, 1, 0);
  STG_B(1, 0, NT > 1 ? 1 : 0);
  WAITVM2();
  BAR();
  for (int it = 0; it < NIT; ++it) {
    const int T = it * 2;
    const int k1 = T + 1;                      // NT even -> always valid
    const int k2 = T + 2 < NT ? T + 2 : NT - 1;
    const int k3 = T + 3 < NT ? T + 3 : NT - 1;
    TILE(0, 1, k1, k2);
    TILE(1, 0, k2, k3);
  }
  // epilogue
#pragma unroll
  for (int cf = 0; cf < 4; ++cf) {
    const int col = tn * 256 + wn * 64 + cf * 16 + lr;
    const float bv = HAS_BIAS ? bias[col] : 0.0f;
#pragma unroll
    for (int rf = 0; rf < 8; ++rf)
#pragma unroll
      for (int rr = 0; rr < 4; ++rr) {
        const int row = tm * 256 + wm * 128 + rf * 16 + lg * 4 + rr;
        const float v = acc[rf][cf][rr] + bv;
        if (OUT_BF16)
          ((unsigned short*)Cout)[(size_t)row * N + col] = f2bf(v);
        else
          ((float*)Cout)[(size_t)row * N + col] = v;
      }
  }
}

// ---------------- RoPE in-place on q,k columns of qkv ----------------
__global__ __launch_bounds__(256) void rope_kernel(
    unsigned short* __restrict__ qkv, const float* __restrict__ cs,
    const float* __restrict__ sn) {
  int idx = blockIdx.x * 256 + threadIdx.x;  // MROWS * 88 * 16 total
  int quad = idx & 15;
  int rest = idx >> 4;
  int slot = rest % 88;
  int row = rest / 88;
  if (row >= MROWS) return;
  int col = slot < NH ? slot * HD : KOFF + (slot - NH) * HD;
  unsigned short* p = qkv + (size_t)row * NQKV + col;
  const float* cp = cs + (size_t)row * HD;
  const float* sp = sn + (size_t)row * HD;
  int d0 = quad * 4;
  float4 c1 = *reinterpret_cast<const float4*>(cp + d0);
  float4 s1 = *reinterpret_cast<const float4*>(sp + d0);
  float4 c2 = *reinterpret_cast<const float4*>(cp + d0 + 64);
  float4 s2 = *reinterpret_cast<const float4*>(sp + d0 + 64);
  ushort4 x1 = *reinterpret_cast<const ushort4*>(p + d0);
  ushort4 x2 = *reinterpret_cast<const ushort4*>(p + d0 + 64);
  ushort4 o1, o2;
  float a, b;
  a = bf2f(x1.x); b = bf2f(x2.x);
  o1.x = f2bf(a * c1.x - b * s1.x); o2.x = f2bf(b * c2.x + a * s2.x);
  a = bf2f(x1.y); b = bf2f(x2.y);
  o1.y = f2bf(a * c1.y - b * s1.y); o2.y = f2bf(b * c2.y + a * s2.y);
  a = bf2f(x1.z); b = bf2f(x2.z);
  o1.z = f2bf(a * c1.z - b * s1.z); o2.z = f2bf(b * c2.z + a * s2.z);
  a = bf2f(x1.w); b = bf2f(x2.w);
  o1.w = f2bf(a * c1.w - b * s1.w); o2.w = f2bf(b * c2.w + a * s2.w);
  *reinterpret_cast<ushort4*>(p + d0) = o1;
  *reinterpret_cast<ushort4*>(p + d0 + 64) = o2;
}

// ---------------- causal GQA flash attention ----------------
// block = 256 thr = 4 waves; each wave owns 32 q rows; KV tile = 64
__global__ __launch_bounds__(256, 2) void attn_kernel(
    const unsigned short* __restrict__ qkv, unsigned short* __restrict__ out) {
  __shared__ unsigned short Ks[64][136];     // row-major K tile, +8 pad
  __shared__ unsigned short Vt[128][64];     // transposed V, group-swizzled
  __shared__ unsigned short Ps[4][32][72];   // per-wave P tile, +8 pad
  const int t = threadIdx.x, lane = t & 63, wave = t >> 6;
  const int lr = lane & 15, lg = lane >> 4;
  const int blk = blockIdx.x;
  const int qt = blk & 7;
  const int bh = blk >> 3;
  const int h = bh % NH, b = bh / NH;
  const int kvh = h / GROUPS;
  const int q0 = qt * 128;
  const int wrow0 = q0 + wave * 32;
  const unsigned short* Qb = qkv + (size_t)(b * SEQ) * NQKV + h * HD;
  const unsigned short* Kb = qkv + (size_t)(b * SEQ) * NQKV + KOFF + kvh * HD;
  const unsigned short* Vb = qkv + (size_t)(b * SEQ) * NQKV + VOFF + kvh * HD;
  bf16x8 qf[2][4];
#pragma unroll
  for (int rb = 0; rb < 2; ++rb)
#pragma unroll
    for (int kk = 0; kk < 4; ++kk)
      qf[rb][kk] = ld_vec<bf16x8>(Qb + (size_t)(wrow0 + rb * 16 + lr) * NQKV +
                                  kk * 32 + lg * 8);
  f32x4 acc[2][8] = {};
  float mrow[2][4], lrow[2][4];
#pragma unroll
  for (int rb = 0; rb < 2; ++rb)
#pragma unroll
    for (int r = 0; r < 4; ++r) { mrow[rb][r] = -__builtin_inff(); lrow[rb][r] = 0.f; }

  const int ntile = (q0 + 128) >> 6;
  for (int tt = 0; tt < ntile; ++tt) {
    const int kv0 = tt * 64;
    __syncthreads();
#pragma unroll
    for (int i = 0; i < 4; ++i) {
      int e = i * 2048 + t * 8;
      int row = e >> 7, colc = e & 127;
      uint4 dk = ld_vec<uint4>(Kb + (size_t)(kv0 + row) * NQKV + colc);
      *reinterpret_cast<uint4*>(&Ks[row][colc]) = dk;
      uint4 dv = ld_vec<uint4>(Vb + (size_t)(kv0 + row) * NQKV + colc);
      const unsigned short* pv = reinterpret_cast<const unsigned short*>(&dv);
#pragma unroll
      for (int j = 0; j < 8; ++j) {
        int dd = colc + j;
        int gp = ((row >> 3) + dd + (dd >> 3)) & 7;
        Vt[dd][(gp << 3) | (row & 7)] = pv[j];
      }
    }
    __syncthreads();
    if (kv0 > wrow0 + 31) continue;
    const bool needMask = (kv0 + 63) > wrow0;
#pragma unroll
    for (int rb = 0; rb < 2; ++rb) {
      f32x4 sf[4] = {};
#pragma unroll
      for (int kk = 0; kk < 4; ++kk) {
#pragma unroll
        for (int cb = 0; cb < 4; ++cb) {
          bf16x8 kfr = ld_vec<bf16x8>(&Ks[cb * 16 + lr][kk * 32 + lg * 8]);
          sf[cb] = __builtin_amdgcn_mfma_f32_16x16x32_bf16(qf[rb][kk], kfr,
                                                           sf[cb], 0, 0, 0);
        }
      }
#pragma unroll
      for (int r = 0; r < 4; ++r) {
        int qrow = wrow0 + rb * 16 + lg * 4 + r;
        float mx = -3.0e38f;
#pragma unroll
        for (int cb = 0; cb < 4; ++cb) {
          float s = sf[cb][r] * ATTN_SCALE;
          if (needMask && (kv0 + cb * 16 + lr) > qrow) s = -__builtin_inff();
          sf[cb][r] = s;
          mx = fmaxf(mx, s);
        }
        mx = fmaxf(mx, __shfl_xor(mx, 1));
        mx = fmaxf(mx, __shfl_xor(mx, 2));
        mx = fmaxf(mx, __shfl_xor(mx, 4));
        mx = fmaxf(mx, __shfl_xor(mx, 8));
        float mold = mrow[rb][r];
        float mnew = fmaxf(mold, mx);
        float sfac = __expf(mold - mnew);
        mrow[rb][r] = mnew;
        float ps = 0.f;
#pragma unroll
        for (int cb = 0; cb < 4; ++cb) {
          float p = __expf(sf[cb][r] - mnew);
          ps += p;
          Ps[wave][rb * 16 + lg * 4 + r][cb * 16 + lr] = f2bf(p);
        }
        ps += __shfl_xor(ps, 1);
        ps += __shfl_xor(ps, 2);
        ps += __shfl_xor(ps, 4);
        ps += __shfl_xor(ps, 8);
        lrow[rb][r] = lrow[rb][r] * sfac + ps;
#pragma unroll
        for (int n = 0; n < 8; ++n) acc[rb][n][r] *= sfac;
      }
    }
#pragma unroll
    for (int kk = 0; kk < 2; ++kk) {
      bf16x8 vf[8];
#pragma unroll
      for (int cb = 0; cb < 8; ++cb) {
        int dd = cb * 16 + lr;
        int gp = (kk * 4 + lg + dd + (dd >> 3)) & 7;
        vf[cb] = ld_vec<bf16x8>(&Vt[dd][gp << 3]);
      }
#pragma unroll
      for (int rb = 0; rb < 2; ++rb) {
        bf16x8 pa = ld_vec<bf16x8>(&Ps[wave][rb * 16 + lr][kk * 32 + lg * 8]);
#pragma unroll
        for (int cb = 0; cb < 8; ++cb)
          acc[rb][cb] = __builtin_amdgcn_mfma_f32_16x16x32_bf16(pa, vf[cb],
                                                                acc[rb][cb], 0, 0, 0);
      }
    }
  }
#pragma unroll
  for (int rb = 0; rb < 2; ++rb)
#pragma unroll
    for (int n = 0; n < 8; ++n)
#pragma unroll
      for (int r = 0; r < 4; ++r) {
        int qrow = wrow0 + rb * 16 + lg * 4 + r;
        float v = acc[rb][n][r] / lrow[rb][r];
        out[(size_t)(b * SEQ + qrow) * QCOLS + h * HD + n * 16 + lr] = f2bf(v);
      }
}

// ---------------- launch ----------------
extern "C" void kernel_launch(void* const* d_in, const int* in_sizes, int n_in,
                              void* d_out, int out_size, void* d_ws,
                              size_t ws_size, hipStream_t stream) {
  const float* hs   = (const float*)d_in[0];
  const float* cosb = (const float*)d_in[1];
  const float* sinb = (const float*)d_in[2];
  const float* q_w  = (const float*)d_in[3];
  const float* q_b  = (const float*)d_in[4];
  const float* k_w  = (const float*)d_in[5];
  const float* k_b  = (const float*)d_in[6];
  const float* v_w  = (const float*)d_in[7];
  const float* v_b  = (const float*)d_in[8];
  const float* o_w  = (const float*)d_in[9];

  char* ws = (char*)d_ws;
  unsigned short* hsB  = (unsigned short*)(ws);                  // 2048x5120
  unsigned short* wqkv = (unsigned short*)(ws + 20971520ll);     // 12288x5120
  unsigned short* wo   = (unsigned short*)(ws + 146800640ll);    // 5120x10240
  unsigned short* qkv  = (unsigned short*)(ws + 251658240ll);    // 2048x12288
  unsigned short* attn = (unsigned short*)(ws + 301989888ll);    // 2048x10240
  float* bqkv          = (float*)(ws + 343932928ll);             // 12288

  cvt_f32_bf16<<<dim3(5120), dim3(256), 0, stream>>>(hs, hsB, (long)MROWS * DMODEL);
  cvt_f32_bf16<<<dim3(25600), dim3(256), 0, stream>>>(q_w, wqkv, (long)QCOLS * DMODEL);
  cvt_f32_bf16<<<dim3(2560), dim3(256), 0, stream>>>(
      k_w, wqkv + (size_t)KOFF * DMODEL, (long)1024 * DMODEL);
  cvt_f32_bf16<<<dim3(2560), dim3(256), 0, stream>>>(
      v_w, wqkv + (size_t)VOFF * DMODEL, (long)1024 * DMODEL);
  cvt_f32_bf16<<<dim3(25600), dim3(256), 0, stream>>>(o_w, wo, (long)5120 * 10240);
  concat_bias<<<dim3(48), dim3(256), 0, stream>>>(q_b, k_b, v_b, bqkv);

  gemm8<1, 1><<<dim3(384), dim3(512), 0, stream>>>(
      hsB, wqkv, bqkv, qkv, MROWS, NQKV, DMODEL, 48);
  rope_kernel<<<dim3(11264), dim3(256), 0, stream>>>(qkv, cosb, sinb);
  attn_kernel<<<dim3(1280), dim3(256), 0, stream>>>(qkv, attn);
  gemm8<0, 0><<<dim3(160), dim3(512), 0, stream>>>(
      attn, wo, nullptr, d_out, MROWS, 5120, 10240, 20);
}

// Round 5
// 898.772 us; speedup vs baseline: 1.5174x; 1.5174x over previous
//
#include <hip/hip_runtime.h>
#include <hip/hip_bf16.h>

#define NH 80
#define NKV 8
#define HD 128
#define GROUPS 10
#define SEQ 1024
#define BATCH 2
#define DMODEL 5120
#define NQKV 12288   // 10240 q + 1024 k + 1024 v
#define MROWS 2048   // B*S
#define QCOLS 10240
#define KOFF 10240
#define VOFF 11264
#define ATTN_SCALE 0.08838834764831845f  // 128^-0.5

typedef __attribute__((ext_vector_type(8))) __bf16 bf16x8;
typedef __attribute__((ext_vector_type(4))) float f32x4;

__device__ inline unsigned short f2bf(float f) {
  unsigned u = __float_as_uint(f);
  u = (u + 0x7fffu + ((u >> 16) & 1u)) >> 16;
  return (unsigned short)u;
}
__device__ inline float bf2f(unsigned short h) {
  return __uint_as_float(((unsigned)h) << 16);
}

template <typename T>
__device__ inline T ld_vec(const void* p) {
  T v;
  __builtin_memcpy(&v, p, sizeof(T));
  return v;
}

__device__ inline void gload_lds16(const void* g, void* l) {
  __builtin_amdgcn_global_load_lds(
      (const __attribute__((address_space(1))) void*)g,
      (__attribute__((address_space(3))) void*)l, 16, 0, 0);
}

// ---------------- fp32 -> bf16 conversion (8 elems/thread) ----------------
__global__ __launch_bounds__(256) void cvt_f32_bf16(
    const float* __restrict__ src, unsigned short* __restrict__ dst, long n) {
  long i = ((long)blockIdx.x * 256 + threadIdx.x) * 8;
  if (i + 8 > n) return;
  float4 a = *reinterpret_cast<const float4*>(src + i);
  float4 b = *reinterpret_cast<const float4*>(src + i + 4);
  union { unsigned short u[8]; uint4 v; } r;
  r.u[0] = f2bf(a.x); r.u[1] = f2bf(a.y); r.u[2] = f2bf(a.z); r.u[3] = f2bf(a.w);
  r.u[4] = f2bf(b.x); r.u[5] = f2bf(b.y); r.u[6] = f2bf(b.z); r.u[7] = f2bf(b.w);
  *reinterpret_cast<uint4*>(dst + i) = r.v;
}

__global__ __launch_bounds__(256) void concat_bias(
    const float* __restrict__ qb, const float* __restrict__ kb,
    const float* __restrict__ vb, float* __restrict__ out) {
  int i = blockIdx.x * 256 + threadIdx.x;
  if (i >= NQKV) return;
  float v;
  if (i < KOFF) v = qb[i];
  else if (i < VOFF) v = kb[i - KOFF];
  else v = vb[i - VOFF];
  out[i] = v;
}

// ---------------- GEMM: C[M,N] = A[M,K] * W[N,K]^T (+bias) ----------------
// r1 structure (proven): 128x128 tile, 4 waves 2x2, each wave 64x64.
// Upgrades: BK=64 (halves the vmcnt0+barrier drains per MFMA) and a bank
// swizzle on the 128B LDS rows: read col ^= ((lr&7)<<4); the global SOURCE of
// global_load_lds carries the same involution (LDS dest linear, rule #21).
template <int OUT_BF16, int HAS_BIAS>
__global__ __launch_bounds__(256, 2) void gemm_bt64(
    const unsigned short* __restrict__ A, const unsigned short* __restrict__ W,
    const float* __restrict__ bias, void* __restrict__ Cout,
    int M, int N, int K) {
  __shared__ unsigned short As[128 * 64];   // 16 KB, rows of 128 B
  __shared__ unsigned short Bs[128 * 64];
  const int t = threadIdx.x;
  const int lane = t & 63, wave = t >> 6;
  const int m0 = blockIdx.y * 128, n0 = blockIdx.x * 128;
  const int wr = (wave >> 1) * 64, wc = (wave & 1) * 64;
  const int lr = lane & 15, lg = lane >> 4;
  // staging geometry (computed once): 4 chunks x (wave,lane) -> row, src col
  int st_row[4], st_col[4];
#pragma unroll
  for (int ch = 0; ch < 4; ++ch) {
    int ol = wave * 1024 + ch * 4096 + lane * 16;  // dest byte in 16 KB tile
    int row = ol >> 7, cb = ol & 127;
    st_row[ch] = row;
    st_col[ch] = cb ^ ((row & 7) << 4);            // involution
  }
  f32x4 acc[4][4] = {};
  const int swz = (lr & 7) << 4;  // read-side: row&7 == lr&7 for fragments
  for (int k0 = 0; k0 < K; k0 += 64) {
#pragma unroll
    for (int ch = 0; ch < 4; ++ch) {
      int od = wave * 1024 + ch * 4096;            // wave-uniform LDS offset
      gload_lds16((const char*)A +
                      ((size_t)(m0 + st_row[ch]) * K + k0) * 2 + st_col[ch],
                  (char*)As + od);
      gload_lds16((const char*)W +
                      ((size_t)(n0 + st_row[ch]) * K + k0) * 2 + st_col[ch],
                  (char*)Bs + od);
    }
    __syncthreads();
    bf16x8 af[4][2], bfr[4][2];
#pragma unroll
    for (int ks = 0; ks < 2; ++ks) {
      int colb = (ks * 64 + lg * 16) ^ swz;
#pragma unroll
      for (int m = 0; m < 4; ++m)
        af[m][ks] =
            ld_vec<bf16x8>((const char*)As + (wr + m * 16 + lr) * 128 + colb);
#pragma unroll
      for (int n = 0; n < 4; ++n)
        bfr[n][ks] =
            ld_vec<bf16x8>((const char*)Bs + (wc + n * 16 + lr) * 128 + colb);
    }
#pragma unroll
    for (int ks = 0; ks < 2; ++ks)
#pragma unroll
      for (int m = 0; m < 4; ++m)
#pragma unroll
        for (int n = 0; n < 4; ++n)
          acc[m][n] = __builtin_amdgcn_mfma_f32_16x16x32_bf16(
              af[m][ks], bfr[n][ks], acc[m][n], 0, 0, 0);
    __syncthreads();
  }
#pragma unroll
  for (int n = 0; n < 4; ++n) {
    int col = n0 + wc + n * 16 + lr;
    float bv = HAS_BIAS ? bias[col] : 0.0f;
#pragma unroll
    for (int m = 0; m < 4; ++m) {
#pragma unroll
      for (int r = 0; r < 4; ++r) {
        int row = m0 + wr + m * 16 + lg * 4 + r;
        float v = acc[m][n][r] + bv;
        if (OUT_BF16)
          ((unsigned short*)Cout)[(size_t)row * N + col] = f2bf(v);
        else
          ((float*)Cout)[(size_t)row * N + col] = v;
      }
    }
  }
}

// ---------------- RoPE in-place on q,k columns of qkv ----------------
__global__ __launch_bounds__(256) void rope_kernel(
    unsigned short* __restrict__ qkv, const float* __restrict__ cs,
    const float* __restrict__ sn) {
  int idx = blockIdx.x * 256 + threadIdx.x;  // MROWS * 88 * 16 total
  int quad = idx & 15;
  int rest = idx >> 4;
  int slot = rest % 88;
  int row = rest / 88;
  if (row >= MROWS) return;
  int col = slot < NH ? slot * HD : KOFF + (slot - NH) * HD;
  unsigned short* p = qkv + (size_t)row * NQKV + col;
  const float* cp = cs + (size_t)row * HD;
  const float* sp = sn + (size_t)row * HD;
  int d0 = quad * 4;
  float4 c1 = *reinterpret_cast<const float4*>(cp + d0);
  float4 s1 = *reinterpret_cast<const float4*>(sp + d0);
  float4 c2 = *reinterpret_cast<const float4*>(cp + d0 + 64);
  float4 s2 = *reinterpret_cast<const float4*>(sp + d0 + 64);
  ushort4 x1 = *reinterpret_cast<const ushort4*>(p + d0);
  ushort4 x2 = *reinterpret_cast<const ushort4*>(p + d0 + 64);
  ushort4 o1, o2;
  float a, b;
  a = bf2f(x1.x); b = bf2f(x2.x);
  o1.x = f2bf(a * c1.x - b * s1.x); o2.x = f2bf(b * c2.x + a * s2.x);
  a = bf2f(x1.y); b = bf2f(x2.y);
  o1.y = f2bf(a * c1.y - b * s1.y); o2.y = f2bf(b * c2.y + a * s2.y);
  a = bf2f(x1.z); b = bf2f(x2.z);
  o1.z = f2bf(a * c1.z - b * s1.z); o2.z = f2bf(b * c2.z + a * s2.z);
  a = bf2f(x1.w); b = bf2f(x2.w);
  o1.w = f2bf(a * c1.w - b * s1.w); o2.w = f2bf(b * c2.w + a * s2.w);
  *reinterpret_cast<ushort4*>(p + d0) = o1;
  *reinterpret_cast<ushort4*>(p + d0 + 64) = o2;
}

// ---------------- causal GQA flash attention ----------------
// block = 256 thr = 4 waves; each wave owns 32 q rows; KV tile = 64
__global__ __launch_bounds__(256, 2) void attn_kernel(
    const unsigned short* __restrict__ qkv, unsigned short* __restrict__ out) {
  __shared__ unsigned short Ks[64][136];     // row-major K tile, +8 pad
  __shared__ unsigned short Vt[128][64];     // transposed V, group-swizzled
  __shared__ unsigned short Ps[4][32][72];   // per-wave P tile, +8 pad
  const int t = threadIdx.x, lane = t & 63, wave = t >> 6;
  const int lr = lane & 15, lg = lane >> 4;
  const int blk = blockIdx.x;
  const int qt = blk & 7;
  const int bh = blk >> 3;
  const int h = bh % NH, b = bh / NH;
  const int kvh = h / GROUPS;
  const int q0 = qt * 128;
  const int wrow0 = q0 + wave * 32;
  const unsigned short* Qb = qkv + (size_t)(b * SEQ) * NQKV + h * HD;
  const unsigned short* Kb = qkv + (size_t)(b * SEQ) * NQKV + KOFF + kvh * HD;
  const unsigned short* Vb = qkv + (size_t)(b * SEQ) * NQKV + VOFF + kvh * HD;
  bf16x8 qf[2][4];
#pragma unroll
  for (int rb = 0; rb < 2; ++rb)
#pragma unroll
    for (int kk = 0; kk < 4; ++kk)
      qf[rb][kk] = ld_vec<bf16x8>(Qb + (size_t)(wrow0 + rb * 16 + lr) * NQKV +
                                  kk * 32 + lg * 8);
  f32x4 acc[2][8] = {};
  float mrow[2][4], lrow[2][4];
#pragma unroll
  for (int rb = 0; rb < 2; ++rb)
#pragma unroll
    for (int r = 0; r < 4; ++r) { mrow[rb][r] = -__builtin_inff(); lrow[rb][r] = 0.f; }

  const int ntile = (q0 + 128) >> 6;
  for (int tt = 0; tt < ntile; ++tt) {
    const int kv0 = tt * 64;
    __syncthreads();
#pragma unroll
    for (int i = 0; i < 4; ++i) {
      int e = i * 2048 + t * 8;
      int row = e >> 7, colc = e & 127;
      uint4 dk = ld_vec<uint4>(Kb + (size_t)(kv0 + row) * NQKV + colc);
      *reinterpret_cast<uint4*>(&Ks[row][colc]) = dk;
      uint4 dv = ld_vec<uint4>(Vb + (size_t)(kv0 + row) * NQKV + colc);
      const unsigned short* pv = reinterpret_cast<const unsigned short*>(&dv);
#pragma unroll
      for (int j = 0; j < 8; ++j) {
        int dd = colc + j;
        int gp = ((row >> 3) + dd + (dd >> 3)) & 7;
        Vt[dd][(gp << 3) | (row & 7)] = pv[j];
      }
    }
    __syncthreads();
    if (kv0 > wrow0 + 31) continue;
    const bool needMask = (kv0 + 63) > wrow0;
#pragma unroll
    for (int rb = 0; rb < 2; ++rb) {
      f32x4 sf[4] = {};
#pragma unroll
      for (int kk = 0; kk < 4; ++kk) {
#pragma unroll
        for (int cb = 0; cb < 4; ++cb) {
          bf16x8 kfr = ld_vec<bf16x8>(&Ks[cb * 16 + lr][kk * 32 + lg * 8]);
          sf[cb] = __builtin_amdgcn_mfma_f32_16x16x32_bf16(qf[rb][kk], kfr,
                                                           sf[cb], 0, 0, 0);
        }
      }
#pragma unroll
      for (int r = 0; r < 4; ++r) {
        int qrow = wrow0 + rb * 16 + lg * 4 + r;
        float mx = -3.0e38f;
#pragma unroll
        for (int cb = 0; cb < 4; ++cb) {
          float s = sf[cb][r] * ATTN_SCALE;
          if (needMask && (kv0 + cb * 16 + lr) > qrow) s = -__builtin_inff();
          sf[cb][r] = s;
          mx = fmaxf(mx, s);
        }
        mx = fmaxf(mx, __shfl_xor(mx, 1));
        mx = fmaxf(mx, __shfl_xor(mx, 2));
        mx = fmaxf(mx, __shfl_xor(mx, 4));
        mx = fmaxf(mx, __shfl_xor(mx, 8));
        float mold = mrow[rb][r];
        float mnew = fmaxf(mold, mx);
        float sfac = __expf(mold - mnew);
        mrow[rb][r] = mnew;
        float ps = 0.f;
#pragma unroll
        for (int cb = 0; cb < 4; ++cb) {
          float p = __expf(sf[cb][r] - mnew);
          ps += p;
          Ps[wave][rb * 16 + lg * 4 + r][cb * 16 + lr] = f2bf(p);
        }
        ps += __shfl_xor(ps, 1);
        ps += __shfl_xor(ps, 2);
        ps += __shfl_xor(ps, 4);
        ps += __shfl_xor(ps, 8);
        lrow[rb][r] = lrow[rb][r] * sfac + ps;
#pragma unroll
        for (int n = 0; n < 8; ++n) acc[rb][n][r] *= sfac;
      }
    }
#pragma unroll
    for (int kk = 0; kk < 2; ++kk) {
      bf16x8 vf[8];
#pragma unroll
      for (int cb = 0; cb < 8; ++cb) {
        int dd = cb * 16 + lr;
        int gp = (kk * 4 + lg + dd + (dd >> 3)) & 7;
        vf[cb] = ld_vec<bf16x8>(&Vt[dd][gp << 3]);
      }
#pragma unroll
      for (int rb = 0; rb < 2; ++rb) {
        bf16x8 pa = ld_vec<bf16x8>(&Ps[wave][rb * 16 + lr][kk * 32 + lg * 8]);
#pragma unroll
        for (int cb = 0; cb < 8; ++cb)
          acc[rb][cb] = __builtin_amdgcn_mfma_f32_16x16x32_bf16(pa, vf[cb],
                                                                acc[rb][cb], 0, 0, 0);
      }
    }
  }
#pragma unroll
  for (int rb = 0; rb < 2; ++rb)
#pragma unroll
    for (int n = 0; n < 8; ++n)
#pragma unroll
      for (int r = 0; r < 4; ++r) {
        int qrow = wrow0 + rb * 16 + lg * 4 + r;
        float v = acc[rb][n][r] / lrow[rb][r];
        out[(size_t)(b * SEQ + qrow) * QCOLS + h * HD + n * 16 + lr] = f2bf(v);
      }
}

// ---------------- launch ----------------
extern "C" void kernel_launch(void* const* d_in, const int* in_sizes, int n_in,
                              void* d_out, int out_size, void* d_ws,
                              size_t ws_size, hipStream_t stream) {
  const float* hs   = (const float*)d_in[0];
  const float* cosb = (const float*)d_in[1];
  const float* sinb = (const float*)d_in[2];
  const float* q_w  = (const float*)d_in[3];
  const float* q_b  = (const float*)d_in[4];
  const float* k_w  = (const float*)d_in[5];
  const float* k_b  = (const float*)d_in[6];
  const float* v_w  = (const float*)d_in[7];
  const float* v_b  = (const float*)d_in[8];
  const float* o_w  = (const float*)d_in[9];

  char* ws = (char*)d_ws;
  unsigned short* hsB  = (unsigned short*)(ws);                  // 2048x5120
  unsigned short* wqkv = (unsigned short*)(ws + 20971520ll);     // 12288x5120
  unsigned short* wo   = (unsigned short*)(ws + 146800640ll);    // 5120x10240
  unsigned short* qkv  = (unsigned short*)(ws + 251658240ll);    // 2048x12288
  unsigned short* attn = (unsigned short*)(ws + 301989888ll);    // 2048x10240
  float* bqkv          = (float*)(ws + 343932928ll);             // 12288

  cvt_f32_bf16<<<dim3(5120), dim3(256), 0, stream>>>(hs, hsB, (long)MROWS * DMODEL);
  cvt_f32_bf16<<<dim3(25600), dim3(256), 0, stream>>>(q_w, wqkv, (long)QCOLS * DMODEL);
  cvt_f32_bf16<<<dim3(2560), dim3(256), 0, stream>>>(
      k_w, wqkv + (size_t)KOFF * DMODEL, (long)1024 * DMODEL);
  cvt_f32_bf16<<<dim3(2560), dim3(256), 0, stream>>>(
      v_w, wqkv + (size_t)VOFF * DMODEL, (long)1024 * DMODEL);
  cvt_f32_bf16<<<dim3(25600), dim3(256), 0, stream>>>(o_w, wo, (long)5120 * 10240);
  concat_bias<<<dim3(48), dim3(256), 0, stream>>>(q_b, k_b, v_b, bqkv);

  gemm_bt64<1, 1><<<dim3(96, 16), dim3(256), 0, stream>>>(
      hsB, wqkv, bqkv, qkv, MROWS, NQKV, DMODEL);
  rope_kernel<<<dim3(11264), dim3(256), 0, stream>>>(qkv, cosb, sinb);
  attn_kernel<<<dim3(1280), dim3(256), 0, stream>>>(qkv, attn);
  gemm_bt64<0, 0><<<dim3(40, 16), dim3(256), 0, stream>>>(
      attn, wo, nullptr, d_out, MROWS, 5120, 10240);
}